// Round 5
// baseline (95.283 us; speedup 1.0000x reference)
//
#include <hip/hip_runtime.h>

#define N_NODES 8192
#define HIDDEN 256
#define OUT_DIM 16
#define CAP 128          // max neighbors stored; binomial max deg ~60 << 128
#define G_ROWS 16        // rows per block in the slow dense GEMM
#define PBLK 512         // pool-partial blocks (both paths write P[PBLK][HIDDEN])
#define NPB (N_NODES / PBLK)   // 16 nodes per pool block
#define EMAX 1024        // LDS edge-stage capacity per block (expected ~64)

// ---------------- K0: zero cnt; v = relu(W1)@W2; flag = (b1==0) -------------
__global__ void k_init(const float* __restrict__ W1, const float* __restrict__ b1,
                       const float* __restrict__ W2, int* __restrict__ cnt,
                       float* __restrict__ v, int* __restrict__ flag) {
    const int t = threadIdx.x;         // 256
    const int bid = blockIdx.x;        // 33
    if (bid < 32) {
        cnt[bid * 256 + t] = 0;
        return;
    }
    // block 32: v and flag (independent of adj)
    float acc = 0.0f;
    for (int k = 0; k < HIDDEN; ++k)
        acc += fmaxf(W1[k], 0.0f) * W2[(size_t)k * HIDDEN + t];   // coalesced
    v[t] = acc;
    __shared__ int nz;
    if (t == 0) nz = 0;
    __syncthreads();
    if (b1[t] != 0.0f) atomicOr(&nz, 1);
    __syncthreads();
    if (t == 0) *flag = (nz == 0) ? 1 : 0;
}

// ---------------- K1: upper-triangle scan, LDS-staged edge scatter ----------
// Phase 1: stream row, append edges (i<<13|j) to LDS (cheap LDS atomics).
// Phase 2: parallel scatter burst — global atomic latencies overlap across lanes
// instead of stalling the scan wave per edge (round-4 lesson).
__device__ __forceinline__ void scan_row_stage(const float* __restrict__ adj, int i,
                                               int t, int* ecnt, int* elist) {
    const uint4* row4 = (const uint4*)(adj + (size_t)i * N_NODES);
    const int k0 = (i + 1) >> 2;       // first uint4 that can contain cols > i
    for (int k = k0 + t; k < N_NODES / 4; k += 256) {
        uint4 vv = row4[k];
        if (vv.x | vv.y | vv.z | vv.w) {   // entries are exactly 0.0f or 1.0f
            int base = k * 4;
            if (vv.x && base + 0 > i) { int p = atomicAdd(ecnt, 1); if (p < EMAX) elist[p] = (i << 13) | (base + 0); }
            if (vv.y && base + 1 > i) { int p = atomicAdd(ecnt, 1); if (p < EMAX) elist[p] = (i << 13) | (base + 1); }
            if (vv.z && base + 2 > i) { int p = atomicAdd(ecnt, 1); if (p < EMAX) elist[p] = (i << 13) | (base + 2); }
            if (vv.w && base + 3 > i) { int p = atomicAdd(ecnt, 1); if (p < EMAX) elist[p] = (i << 13) | (base + 3); }
        }
    }
}

__global__ void k_scan(const float* __restrict__ adj, int* __restrict__ cnt,
                       int* __restrict__ nbr) {
    const int t = threadIdx.x;             // 256
    const int ia = blockIdx.x;             // 0..4095
    const int ib = N_NODES - 1 - ia;       // 8191..4096
    __shared__ int ecnt;
    __shared__ int elist[EMAX];
    if (t == 0) ecnt = 0;
    __syncthreads();
    scan_row_stage(adj, ia, t, &ecnt, elist);   // span 8191-ia elems
    scan_row_stage(adj, ib, t, &ecnt, elist);   // span ia elems (combined ~8191)
    __syncthreads();
    int ne = ecnt; if (ne > EMAX) ne = EMAX;
    for (int e = t; e < ne; e += 256) {
        const int packed = elist[e];
        const int i = packed >> 13;
        const int j = packed & (N_NODES - 1);
        int p = atomicAdd(&cnt[i], 1);
        if (p < CAP) nbr[(size_t)i * CAP + p] = j;
        int q = atomicAdd(&cnt[j], 1);
        if (q < CAP) nbr[(size_t)j * CAP + q] = i;
    }
}

// ---------------- K2: s_i = di*(di + sum dinv_j); tt_i = di*s_i; dinv -------
__global__ void k_srow(const int* __restrict__ cnt, const int* __restrict__ nbr,
                       float* __restrict__ s, float* __restrict__ tt,
                       float* __restrict__ dinv) {
    const int w = threadIdx.x >> 6;    // wave 0..3, one node per wave
    const int lane = threadIdx.x & 63;
    const int i = blockIdx.x * 4 + w;
    const int c0 = cnt[i];
    const int c = c0 < CAP ? c0 : CAP;
    const float di = rsqrtf((float)(c0 + 1));   // +1 self loop
    float p = 0.0f;
    for (int k = lane; k < c; k += 64)
        p += rsqrtf((float)(cnt[nbr[(size_t)i * CAP + k]] + 1));
    #pragma unroll
    for (int off = 32; off > 0; off >>= 1) p += __shfl_down(p, off);
    if (lane == 0) {
        const float si = di * (di + p);
        s[i] = si; tt[i] = di * si; dinv[i] = di;
    }
}

// ---------------- SLOW K3: g = relu(s (x) W1 + b1) @ W2  (predicated) -------
__global__ void k_gemm(const float* __restrict__ s, const float* __restrict__ W1,
                       const float* __restrict__ b1, const float* __restrict__ W2,
                       const int* __restrict__ flag, float* __restrict__ g) {
    if (*flag) return;                         // fast path active: no-op
    const int t = threadIdx.x;
    const int row0 = blockIdx.x * G_ROWS;
    __shared__ float hT[HIDDEN][G_ROWS];
    const float w1 = W1[t];
    const float bb = b1[t];
    for (int r = 0; r < G_ROWS; ++r)
        hT[t][r] = fmaxf(s[row0 + r] * w1 + bb, 0.0f);
    __syncthreads();

    float acc[G_ROWS];
    #pragma unroll
    for (int r = 0; r < G_ROWS; ++r) acc[r] = 0.0f;
    for (int k = 0; k < HIDDEN; ++k) {
        const float w2 = W2[(size_t)k * HIDDEN + t];
        const float4 h0 = *(const float4*)&hT[k][0];
        const float4 h1 = *(const float4*)&hT[k][4];
        const float4 h2 = *(const float4*)&hT[k][8];
        const float4 h3 = *(const float4*)&hT[k][12];
        acc[0]  += h0.x * w2;  acc[1]  += h0.y * w2;  acc[2]  += h0.z * w2;  acc[3]  += h0.w * w2;
        acc[4]  += h1.x * w2;  acc[5]  += h1.y * w2;  acc[6]  += h1.z * w2;  acc[7]  += h1.w * w2;
        acc[8]  += h2.x * w2;  acc[9]  += h2.y * w2;  acc[10] += h2.z * w2;  acc[11] += h2.w * w2;
        acc[12] += h3.x * w2;  acc[13] += h3.y * w2;  acc[14] += h3.z * w2;  acc[15] += h3.w * w2;
    }
    #pragma unroll
    for (int r = 0; r < G_ROWS; ++r)
        g[(size_t)(row0 + r) * HIDDEN + t] = acc[r];
}

// ---------------- K4: pool partials, both paths -> P[PBLK][HIDDEN] ----------
__global__ void k_pool(const int* __restrict__ cnt, const int* __restrict__ nbr,
                       const float* __restrict__ s, const float* __restrict__ tt,
                       const float* __restrict__ dinv, const float* __restrict__ g,
                       const float* __restrict__ v, const float* __restrict__ b2,
                       const int* __restrict__ flag, float* __restrict__ P) {
    const int t = threadIdx.x;
    const int bid = blockIdx.x;            // 512
    if (*flag) {
        // FAST: q_i = di*(di*s_i + sum tt_j); pp = sum_n relu(q_n*v_t + b2_t)
        __shared__ float qsh[NPB];
        const int w = t >> 6, lane = t & 63;
        #pragma unroll
        for (int n = 0; n < NPB / 4; ++n) {        // 4 nodes per wave
            const int i = bid * NPB + w * (NPB / 4) + n;
            const int c0 = cnt[i];
            const int c = c0 < CAP ? c0 : CAP;
            const float di = rsqrtf((float)(c0 + 1));
            float p = 0.0f;
            for (int k = lane; k < c; k += 64) p += tt[nbr[(size_t)i * CAP + k]];
            #pragma unroll
            for (int off = 32; off > 0; off >>= 1) p += __shfl_down(p, off);
            if (lane == 0) qsh[w * (NPB / 4) + n] = di * (di * s[i] + p);
        }
        __syncthreads();
        const float vc = v[t], bc = b2[t];
        float pp = 0.0f;
        #pragma unroll
        for (int n = 0; n < NPB; ++n) pp += fmaxf(qsh[n] * vc + bc, 0.0f);
        P[(size_t)bid * HIDDEN + t] = pp;
    } else {
        // SLOW: aggregate g + bias + relu + partial pool
        const float bb2 = b2[t];
        float pool = 0.0f;
        for (int n = 0; n < NPB; ++n) {
            const int i = bid * NPB + n;
            const float di = dinv[i];
            float val = di * g[(size_t)i * HIDDEN + t];
            const int c0 = cnt[i];
            const int c = c0 < CAP ? c0 : CAP;
            const int* nb = nbr + (size_t)i * CAP;
            for (int k = 0; k < c; ++k) {
                const int j = nb[k];
                val += dinv[j] * g[(size_t)j * HIDDEN + t];
            }
            val *= di;
            pool += fmaxf(val + bb2, 0.0f);
        }
        P[(size_t)bid * HIDDEN + t] = pool;
    }
}

// ---------------- K5: pooled = sum P; out = pooled @ Wfc + bfc --------------
__global__ void k_finish(const float* __restrict__ P, const float* __restrict__ Wfc,
                         const float* __restrict__ bfc, float* __restrict__ out) {
    const int t = threadIdx.x;      // 256
    float a0 = 0.f, a1 = 0.f, a2 = 0.f, a3 = 0.f;
    #pragma unroll 8
    for (int r = 0; r < PBLK; r += 4) {
        a0 += P[(size_t)(r + 0) * HIDDEN + t];
        a1 += P[(size_t)(r + 1) * HIDDEN + t];
        a2 += P[(size_t)(r + 2) * HIDDEN + t];
        a3 += P[(size_t)(r + 3) * HIDDEN + t];
    }
    __shared__ float pooled[HIDDEN];
    pooled[t] = (a0 + a1) + (a2 + a3);
    __syncthreads();
    const int o = t & 15, kg = t >> 4;
    float pr = 0.0f;
    for (int k = kg; k < HIDDEN; k += 16) pr += pooled[k] * Wfc[k * OUT_DIM + o];
    __shared__ float red[256];
    red[t] = pr;
    __syncthreads();
    if (t < OUT_DIM) {
        float sum = bfc[t];
        #pragma unroll
        for (int gg = 0; gg < 16; ++gg) sum += red[gg * 16 + t];
        out[t] = sum;
    }
}

extern "C" void kernel_launch(void* const* d_in, const int* in_sizes, int n_in,
                              void* d_out, int out_size, void* d_ws, size_t ws_size,
                              hipStream_t stream) {
    const float* adj = (const float*)d_in[0];
    const float* W1  = (const float*)d_in[1];
    const float* b1  = (const float*)d_in[2];
    const float* W2  = (const float*)d_in[3];
    const float* b2  = (const float*)d_in[4];
    const float* Wfc = (const float*)d_in[5];
    const float* bfc = (const float*)d_in[6];
    float* out = (float*)d_out;

    // workspace layout (16 MiB used)
    char* ws = (char*)d_ws;
    int*   cnt  = (int*)  (ws + 0);                 // 32 KB
    float* s    = (float*)(ws + (32 << 10));        // 32 KB
    float* tt   = (float*)(ws + (64 << 10));        // 32 KB
    float* dinv = (float*)(ws + (96 << 10));        // 32 KB (slow path)
    float* v    = (float*)(ws + (128 << 10));       // 1 KB
    int*   flag = (int*)  (ws + (132 << 10));       // 4 B
    float* P    = (float*)(ws + (256 << 10));       // 512 KB (512 x 256)
    int*   nbr  = (int*)  (ws + (2 << 20));         // 4 MB
    float* g    = (float*)(ws + (8 << 20));         // 8 MB (slow path only)

    k_init  <<<33, 256, 0, stream>>>(W1, b1, W2, cnt, v, flag);
    k_scan  <<<N_NODES / 2, 256, 0, stream>>>(adj, cnt, nbr);
    k_srow  <<<N_NODES / 4, 256, 0, stream>>>(cnt, nbr, s, tt, dinv);
    k_gemm  <<<N_NODES / G_ROWS, 256, 0, stream>>>(s, W1, b1, W2, flag, g);
    k_pool  <<<PBLK, 256, 0, stream>>>(cnt, nbr, s, tt, dinv, g, v, b2, flag, P);
    k_finish<<<1, 256, 0, stream>>>(P, Wfc, bfc, out);
}